// Round 1
// baseline (132.874 us; speedup 1.0000x reference)
//
#include <hip/hip_runtime.h>

// CostVolume: x,y fp32 [2,64,96,320]; GROUP=8 -> 8 groups x 8 channels.
// Per group: L2-normalize the 8-channel vector per pixel (+EPS on the norm),
// cost[b,g,d,h,j] = sum_cc | xn[cc][h][j] - yn[cc][h][j-d] |, yn term = 0
// when j < d (left zero-pad -> cost = sum|xn|). Output [2,8,49,96,320] fp32.
//
// v2 structure: one block per (b,g, h-pair): 320 threads = 2 rows x 160
// column-pairs; each thread owns 2 adjacent columns (j, j+1).
//  - float2 global loads/stores (8B/lane, 512B/wave-instr).
//  - Sliding-window register reuse: Y(j+1-(d+1)) == Y(j-d), so each
//    disparity step needs only ONE fresh LDS position per thread
//    (2x ds_read_b128 per 2 output pixels, 4x less than v1).
//  - LDS split by column parity: fresh position 2q-d has uniform parity
//    across lanes -> reads stay 16B lane-stride, conflict-free.

#define MAXDISP 48
#define NDISP   49
#define HH      96
#define WW      320
#define HW      (HH * WW)      // 30720
#define EPSN    1e-5f

__global__ __launch_bounds__(320) void cost_volume_kernel(
    const float* __restrict__ x, const float* __restrict__ y,
    float* __restrict__ out)
{
    // [row][parity][half][idx] ; half0 = ch0..3, half1 = ch4..7 ; 20,480 B
    __shared__ float4 ylds[2][2][2][WW / 2];

    const int tid = threadIdx.x;
    const int q   = tid % 160;          // column-pair index, 0..159
    const int r   = tid / 160;          // row within block, 0..1
    const int j   = 2 * q;              // left column of the pair

    const int blk = blockIdx.x;         // 0..767
    const int hp  = blk % (HH / 2);     // h-pair, 0..47
    const int bg  = blk / (HH / 2);     // b*8+g, 0..15
    const int h   = hp * 2 + r;

    // input flat idx = (bg*8 + cc)*HW + h*WW + j   (j even -> 8B aligned)
    const int inBase = bg * 8 * HW + h * WW + j;

    float xa[8], xb[8], ya[8], yb[8];   // a = col j, b = col j+1
    float xsa = 0.f, xsb = 0.f, ysa = 0.f, ysb = 0.f;
#pragma unroll
    for (int cc = 0; cc < 8; ++cc) {
        const float2 xi = *reinterpret_cast<const float2*>(x + inBase + cc * HW);
        const float2 yi = *reinterpret_cast<const float2*>(y + inBase + cc * HW);
        xa[cc] = xi.x; xb[cc] = xi.y;
        ya[cc] = yi.x; yb[cc] = yi.y;
        xsa += xi.x * xi.x; xsb += xi.y * xi.y;
        ysa += yi.x * yi.x; ysb += yi.y * yi.y;
    }
    const float xia = 1.f / (sqrtf(xsa) + EPSN);
    const float xib = 1.f / (sqrtf(xsb) + EPSN);
    const float yia = 1.f / (sqrtf(ysa) + EPSN);
    const float yib = 1.f / (sqrtf(ysb) + EPSN);

    float sAbsA = 0.f, sAbsB = 0.f;
#pragma unroll
    for (int cc = 0; cc < 8; ++cc) {
        xa[cc] *= xia; xb[cc] *= xib;
        ya[cc] *= yia; yb[cc] *= yib;
        sAbsA += fabsf(xa[cc]);
        sAbsB += fabsf(xb[cc]);
    }

    // col j   (even parity 0) -> ylds[r][0][*][q]
    // col j+1 (odd  parity 1) -> ylds[r][1][*][q]
    ylds[r][0][0][q] = make_float4(ya[0], ya[1], ya[2], ya[3]);
    ylds[r][0][1][q] = make_float4(ya[4], ya[5], ya[6], ya[7]);
    ylds[r][1][0][q] = make_float4(yb[0], yb[1], yb[2], yb[3]);
    ylds[r][1][1][q] = make_float4(yb[4], yb[5], yb[6], yb[7]);
    __syncthreads();

    const float4* ldsE = &ylds[r][0][0][0];   // even positions, [half][160]
    const float4* ldsO = &ylds[r][1][0][0];   // odd  positions

    // yp = Y(j - d)  (col j operand), yc = Y(j+1 - d)  (col j+1 operand)
    float4 yp0 = ldsE[q],       yp1 = ldsE[160 + q];
    float4 yc0 = ldsO[q],       yc1 = ldsO[160 + q];

    // fresh read for iteration d targets position j-d-1, parity (d+1)&1:
    // d=0 -> odd, alternating thereafter.
    const float4* bcur = ldsO;
    const float4* bnxt = ldsE;

    float* outp = out + bg * (NDISP * HW) + h * WW + j;

#pragma unroll 7
    for (int d = 0; d < NDISP; ++d) {
        float c0 = fabsf(xa[0] - yp0.x) + fabsf(xa[1] - yp0.y)
                 + fabsf(xa[2] - yp0.z) + fabsf(xa[3] - yp0.w)
                 + fabsf(xa[4] - yp1.x) + fabsf(xa[5] - yp1.y)
                 + fabsf(xa[6] - yp1.z) + fabsf(xa[7] - yp1.w);
        float c1 = fabsf(xb[0] - yc0.x) + fabsf(xb[1] - yc0.y)
                 + fabsf(xb[2] - yc0.z) + fabsf(xb[3] - yc0.w)
                 + fabsf(xb[4] - yc1.x) + fabsf(xb[5] - yc1.y)
                 + fabsf(xb[6] - yc1.z) + fabsf(xb[7] - yc1.w);
        c0 = (d <= j)     ? c0 : sAbsA;   // j-d   < 0 -> pure |xn| sum
        c1 = (d <= j + 1) ? c1 : sAbsB;   // j+1-d < 0
        *reinterpret_cast<float2*>(outp) = make_float2(c0, c1);
        outp += HW;

        // slide: col j+1's next operand is col j's current one
        yc0 = yp0; yc1 = yp1;
        const int pn  = j - d - 1;
        const int idx = (pn > 0 ? pn : 0) >> 1;   // clamped; value unused if pn<0
        yp0 = bcur[idx];
        yp1 = bcur[160 + idx];
        const float4* t = bcur; bcur = bnxt; bnxt = t;
    }
}

extern "C" void kernel_launch(void* const* d_in, const int* in_sizes, int n_in,
                              void* d_out, int out_size, void* d_ws, size_t ws_size,
                              hipStream_t stream) {
    const float* x = (const float*)d_in[0];
    const float* y = (const float*)d_in[1];
    float* out = (float*)d_out;
    // grid = B * GROUP * H/2 = 2*8*48 = 768 blocks (3 per CU exactly)
    dim3 grid(2 * 8 * (HH / 2));
    dim3 block(320);
    cost_volume_kernel<<<grid, block, 0, stream>>>(x, y, out);
}